// Round 1
// baseline (188.440 us; speedup 1.0000x reference)
//
#include <hip/hip_runtime.h>
#include <hip/hip_bf16.h>

// out[b,n] = prod_d psi((x[b,d]-c[n,d])/s[n,d]),  psi(z)=(1-z^2)exp(-z^2/2)
// Factorization: prod psi = [prod(1-z^2)] * exp(-0.5*sum z^2) per 16-d group
// (per-lane partial product <= 80^8 ~ 1.7e15, merged ~3e30 < 3.4e38 fp32 max).
// fp32-only: any f16 path puts ~1e-3 rel error into the exponent -> output
// scales by e^0.064, 11 orders above the 1.7e-18 absmax threshold.
//
// R9: R8 structure + pp staging through LDS with async global_load_lds.
// Rationale: R8's wavelet ran ~38us vs a 13.7us VALU-issue floor (top-5
// rocprof rows are all 41us harness fills -> wavelet < 41us; ~35-40% VALU
// eff). Stalls: 8 dependent dwordx4 pp loads at every chunk start (~200cy
// L2, 8 waves in lockstep), duplicated 4x across the block's waves, and
// un-prefetchable in VGPRs without breaking the 64-VGPR/8-wave cliff.
// Fix: double-buffered LDS tile ppt[2][8][64] (16 KB; 8 blocks x 16 KB =
// 128 KB <= 160 KB, occupancy kept), filled by global_load_lds width=16
// (2 per wave per chunk), prefetched one chunk ahead. __syncthreads'
// vmcnt(0) drain is safe: chunk h+1's loads are issued AFTER barrier h and
// consumed only after barrier h+1 -> a full chunk of compute (~1100cy)
// hides the latency. Reads become conflict-free ds_read_b128 (lane*16B).
//
// Launch-bounds rule (measured R2/R4/R5): 2nd arg w caps VGPR at 256/w.
// w=4 -> cap 64. VGPR budget: cp/rs 32 + acc 8 + temps ~14 = ~56.

#define DD 64
#define BSTRIP 8    // b rows per wave

typedef float v2f __attribute__((ext_vector_type(2)));

__global__ __launch_bounds__(256)
void prep(const float* __restrict__ c, const float* __restrict__ s,
          float4* __restrict__ pp, int N) {
    int i = blockIdx.x * 256 + threadIdx.x;   // over (DD/2)*N
    if (i < (DD / 2) * N) {
        int dp = i / N, n = i - dp * N;
        float r0 = 1.0f / s[n * DD + 2 * dp];
        float r1 = 1.0f / s[n * DD + 2 * dp + 1];
        pp[i] = make_float4(c[n * DD + 2 * dp] * r0,
                            c[n * DD + 2 * dp + 1] * r1, r0, r1);
    }
}

__global__ __launch_bounds__(256, 4)
void wavelet_kernel(const float* __restrict__ x,
                    const float4* __restrict__ pp,
                    float* __restrict__ out, int B, int N) {
    // double-buffered param tile: [buf][dp-pair-row][n-lane], 16 KB
    __shared__ float4 ppt[2][8][64];

    int t = threadIdx.x;
    int lane = t & 63;
    int wv = __builtin_amdgcn_readfirstlane(t >> 6);   // wave-uniform
    int n0 = blockIdx.y * 64;
    int n = n0 + lane;                                 // lane-private column
    int b0 = (blockIdx.x * 4 + wv) * BSTRIP;           // wave-uniform strip

    // async stage of chunk h into ppt[buf]: wave wv fills rows 2wv, 2wv+1.
    // LDS dest is wave-uniform base (+ lane*16 by HW); global src per-lane.
#define STAGE(h, buf)                                                         \
    {                                                                         \
        _Pragma("unroll")                                                     \
        for (int j = 0; j < 2; ++j) {                                         \
            int i = 2 * wv + j;                                               \
            const float4* g = pp + (size_t)((h) * 8 + i) * N + n0 + lane;     \
            __builtin_amdgcn_global_load_lds(                                 \
                (const __attribute__((address_space(1))) void*)g,             \
                (__attribute__((address_space(3))) void*)&ppt[buf][i][0],     \
                16, 0, 0);                                                    \
        }                                                                     \
    }

    STAGE(0, 0);

    float acc[BSTRIP];
#pragma unroll
    for (int bi = 0; bi < BSTRIP; ++bi) acc[bi] = 1.0f;

#pragma unroll
    for (int h = 0; h < 4; ++h) {          // 4 chunks of 16 d (= overflow group)
        // drains this wave's vmcnt then joins barrier -> ppt[h&1] fully
        // resident (all waves' global_load_lds landed) before any read.
        __syncthreads();
        if (h < 3) STAGE(h + 1, (h + 1) & 1);   // prefetch next chunk

        // params for this chunk: conflict-free ds_read_b128, lane = n
        v2f cp[8], rs[8];
#pragma unroll
        for (int i = 0; i < 8; ++i) {
            float4 q = ppt[h & 1][i][lane];
            cp[i] = (v2f){q.x, q.y};
            rs[i] = (v2f){q.z, q.w};
        }

#pragma unroll
        for (int bi = 0; bi < BSTRIP; ++bi) {
            // x slice: wave-uniform address -> scalar/broadcast loads
            const float4* xq =
                (const float4*)(x + (size_t)(b0 + bi) * DD + h * 16);
            float4 X0 = xq[0];
            float4 X1 = xq[1];
            float4 X2 = xq[2];
            float4 X3 = xq[3];
            float xs[16] = {X0.x, X0.y, X0.z, X0.w,
                            X1.x, X1.y, X1.z, X1.w,
                            X2.x, X2.y, X2.z, X2.w,
                            X3.x, X3.y, X3.z, X3.w};
            v2f p  = {1.0f, 1.0f};
            v2f s2 = {0.0f, 0.0f};
#pragma unroll
            for (int k = 0; k < 8; ++k) {          // 8 d-pairs = 16 d
                v2f xv = {xs[2 * k], xs[2 * k + 1]};
                v2f z = __builtin_elementwise_fma(xv, rs[k], -cp[k]);
                v2f w = z * z;
                p = __builtin_elementwise_fma(-w, p, p);
                s2 += w;
            }
            // exp(-0.5*s) = exp2(-0.72134752*s), one per 16-d group
            acc[bi] *= (p.x * p.y) *
                       __builtin_exp2f(-0.72134752f * (s2.x + s2.y));
        }
    }

    // stores: lanes = consecutive n -> coalesced
#pragma unroll
    for (int bi = 0; bi < BSTRIP; ++bi)
        out[(size_t)(b0 + bi) * N + n] = acc[bi];
#undef STAGE
}

extern "C" void kernel_launch(void* const* d_in, const int* in_sizes, int n_in,
                              void* d_out, int out_size, void* d_ws, size_t ws_size,
                              hipStream_t stream) {
    const float* x = (const float*)d_in[0];
    const float* c = (const float*)d_in[1];
    const float* s = (const float*)d_in[2];
    float* out = (float*)d_out;

    int B = in_sizes[0] / DD;    // 8192
    int N = in_sizes[1] / DD;    // 512

    float4* pp = (float4*)d_ws;  // (DD/2)*N*16 B = 256 KB

    int total = (DD / 2) * N;
    prep<<<(total + 255) / 256, 256, 0, stream>>>(c, s, pp, N);

    // grid: x = b-strip groups (4 waves x 8 rows = 32 rows/block), y = n/64
    dim3 grid(B / (4 * BSTRIP), N / 64);   // 256 x 8 = 2048 blocks
    wavelet_kernel<<<grid, 256, 0, stream>>>(x, pp, out, B, N);
}

// Round 2
// 185.443 us; speedup vs baseline: 1.0162x; 1.0162x over previous
//
#include <hip/hip_runtime.h>
#include <hip/hip_bf16.h>

// out[b,n] = prod_d psi((x[b,d]-c[n,d])/s[n,d]),  psi(z)=(1-z^2)exp(-z^2/2)
// Factorization: per 8-d group, prod psi = [prod(1-z^2)] * exp2(-0.7213*sum z^2).
// Each 8-d factor is a partial psi-product with |psi|<=1 -> acc in [0,1],
// no overflow possible. fp32-only (f16 would put ~1e-3 into the exponent).
//
// R10: R9's LDS staging idea, spill-fixed. R9 post-mortem: wavelet rows
// showed WRITE 270 MB / FETCH 212 MB vs 16.7/20 MB logical -> scratch
// spill at the 64-VGPR launch_bounds cap (~450 MB phantom traffic at
// 3.5 TB/s = the 140 us). Fix: halve resident params. Stage pp at 8-d
// half-chunk granularity: pr0..pr3 (16 VGPR) instead of cp/rs (32), with
// ds_read_b128 landing DIRECTLY in the resident float4s (no extraction
// temps). exp2 per 8-d group (+5% trans issue, removes overflow coupling).
// LDS ppt[2][4][64] = 8 KB/block (64 KB/CU @ 8 blocks). One
// global_load_lds per wave per half-chunk, prefetched one ahead; the
// __syncthreads vmcnt drain lands ~600cy after issue (L2 hit ~200cy).
// Budget: pr 16 + acc 8 + temps ~8 + addr ~8 = ~44-50 < 64 -> 8 waves/SIMD.
//
// Launch-bounds rule (measured R2/R4/R5): 2nd arg w caps VGPR at 256/w.

#define DD 64
#define BSTRIP 8    // b rows per wave

typedef float v2f __attribute__((ext_vector_type(2)));

__global__ __launch_bounds__(256)
void prep(const float* __restrict__ c, const float* __restrict__ s,
          float4* __restrict__ pp, int N) {
    int i = blockIdx.x * 256 + threadIdx.x;   // over (DD/2)*N
    if (i < (DD / 2) * N) {
        int dp = i / N, n = i - dp * N;
        float r0 = 1.0f / s[n * DD + 2 * dp];
        float r1 = 1.0f / s[n * DD + 2 * dp + 1];
        pp[i] = make_float4(c[n * DD + 2 * dp] * r0,
                            c[n * DD + 2 * dp + 1] * r1, r0, r1);
    }
}

__global__ __launch_bounds__(256, 4)
void wavelet_kernel(const float* __restrict__ x,
                    const float4* __restrict__ pp,
                    float* __restrict__ out, int B, int N) {
    // double-buffered half-chunk param tile: [buf][dp-pair-row][n-lane], 8 KB
    __shared__ float4 ppt[2][4][64];

    int t = threadIdx.x;
    int lane = t & 63;
    int wv = __builtin_amdgcn_readfirstlane(t >> 6);   // wave-uniform
    int n0 = blockIdx.y * 64;
    int n = n0 + lane;                                 // lane-private column
    int b0 = (blockIdx.x * 4 + wv) * BSTRIP;           // wave-uniform strip

    // async stage of half-chunk hb into ppt[buf]: wave wv fills row wv.
    // LDS dest wave-uniform base (+ lane*16 by HW); global src per-lane.
#define STAGE(hb, buf)                                                        \
    {                                                                         \
        const float4* g = pp + (size_t)((hb) * 4 + wv) * N + n0 + lane;       \
        __builtin_amdgcn_global_load_lds(                                     \
            (const __attribute__((address_space(1))) void*)g,                 \
            (__attribute__((address_space(3))) void*)&ppt[buf][wv][0],        \
            16, 0, 0);                                                        \
    }

    STAGE(0, 0);

    float acc[BSTRIP];
#pragma unroll
    for (int bi = 0; bi < BSTRIP; ++bi) acc[bi] = 1.0f;

    // one 8-d pair-group: z=(x-c)/s via fma, w=z^2, p*=(1-w), s2+=w
#define PAIR(PR, XA, XB)                                                      \
    {                                                                         \
        v2f xv = {XA, XB};                                                    \
        v2f cp = {PR.x, PR.y};                                                \
        v2f rv = {PR.z, PR.w};                                                \
        v2f z = __builtin_elementwise_fma(xv, rv, -cp);                       \
        v2f w = z * z;                                                        \
        p = __builtin_elementwise_fma(-w, p, p);                              \
        s2 += w;                                                              \
    }

#pragma unroll
    for (int hb = 0; hb < 8; ++hb) {       // 8 half-chunks of 8 d
        // drains this wave's vmcnt then joins barrier -> ppt[hb&1] fully
        // resident (all 4 waves' global_load_lds landed) before any read.
        __syncthreads();
        if (hb < 7) STAGE(hb + 1, (hb + 1) & 1);   // prefetch next half

        // resident params for this half-chunk: conflict-free ds_read_b128
        // landing directly in the registers used by the bi-loop.
        float4 pr0 = ppt[hb & 1][0][lane];
        float4 pr1 = ppt[hb & 1][1][lane];
        float4 pr2 = ppt[hb & 1][2][lane];
        float4 pr3 = ppt[hb & 1][3][lane];

#pragma unroll
        for (int bi = 0; bi < BSTRIP; ++bi) {
            // x slice: wave-uniform address -> scalar/broadcast loads
            const float4* xq =
                (const float4*)(x + (size_t)(b0 + bi) * DD + hb * 8);
            float4 X0 = xq[0];
            float4 X1 = xq[1];
            v2f p  = {1.0f, 1.0f};
            v2f s2 = {0.0f, 0.0f};
            PAIR(pr0, X0.x, X0.y)
            PAIR(pr1, X0.z, X0.w)
            PAIR(pr2, X1.x, X1.y)
            PAIR(pr3, X1.z, X1.w)
            // exp(-0.5*s) = exp2(-0.72134752*s), one per 8-d group
            acc[bi] *= (p.x * p.y) *
                       __builtin_exp2f(-0.72134752f * (s2.x + s2.y));
        }
    }

    // stores: lanes = consecutive n -> coalesced
#pragma unroll
    for (int bi = 0; bi < BSTRIP; ++bi)
        out[(size_t)(b0 + bi) * N + n] = acc[bi];
#undef PAIR
#undef STAGE
}

extern "C" void kernel_launch(void* const* d_in, const int* in_sizes, int n_in,
                              void* d_out, int out_size, void* d_ws, size_t ws_size,
                              hipStream_t stream) {
    const float* x = (const float*)d_in[0];
    const float* c = (const float*)d_in[1];
    const float* s = (const float*)d_in[2];
    float* out = (float*)d_out;

    int B = in_sizes[0] / DD;    // 8192
    int N = in_sizes[1] / DD;    // 512

    float4* pp = (float4*)d_ws;  // (DD/2)*N*16 B = 256 KB

    int total = (DD / 2) * N;
    prep<<<(total + 255) / 256, 256, 0, stream>>>(c, s, pp, N);

    // grid: x = b-strip groups (4 waves x 8 rows = 32 rows/block), y = n/64
    dim3 grid(B / (4 * BSTRIP), N / 64);   // 256 x 8 = 2048 blocks
    wavelet_kernel<<<grid, 256, 0, stream>>>(x, pp, out, B, N);
}

// Round 3
// 86.747 us; speedup vs baseline: 2.1723x; 2.1378x over previous
//
#include <hip/hip_runtime.h>

// out[b,n] = prod_d psi((x[b,d]-c[n,d])/s[n,d]),  psi(z)=(1-z^2)exp(-z^2/2)
// Factorization: per 16-d group, prod psi = [prod(1-z^2)] * exp2(-0.7213*sum z^2)
// (per-lane partial product <= 80^8 ~ 1.7e15, merged ~3e30 < 3.4e38 fp32 max).
// fp32-only: any f16 path puts ~1e-3 rel error into the exponent.
//
// R11: kill the scalar-memory x path; revert the R9/R10 barrier-pipelined
// pp staging (post-mortem: at cap-64, fully-unrolled barrier loop +
// global_load_lds spilled ~460 B/thread scratch -> 258 MB phantom WRITE,
// 128-201us; param residency was NOT the cause). Diagnostic for the real
// R8 stall: R7(4 waves)==R8(8 waves) at ~84us -> the ~24us gap over the
// 13.7us VALU floor is wave-count-INSENSITIVE -> throughput-serialized
// shared resource, not latency. Suspect: per-(h,bi) s_load_dwordx4 of x
// thrash the per-CU scalar K$ (8 resident strips x 8KB >> K$), ~128
// L2-latency scalar misses/wave through a shallow shared MSHR pool.
// Fix: stage the 32x64 x strip in LDS once (coalesced, ONE barrier, plain
// ds_write - no global_load_lds), inner loop reads x via wave-uniform
// ds_read_b128 broadcasts (conflict-free, no vmcnt, no K$).
// Cap relaxed to 128 (launch_bounds(256,2)): R7 proved 4 waves/SIMD is
// enough; headroom lets the compiler hoist next-chunk pp loads.

#define DD 64
#define BSTRIP 8    // b rows per wave; 4 waves -> 32 rows per block

typedef float v2f __attribute__((ext_vector_type(2)));

__global__ __launch_bounds__(256)
void prep(const float* __restrict__ c, const float* __restrict__ s,
          float4* __restrict__ pp, int N) {
    int i = blockIdx.x * 256 + threadIdx.x;   // over (DD/2)*N
    if (i < (DD / 2) * N) {
        int dp = i / N, n = i - dp * N;
        float r0 = 1.0f / s[n * DD + 2 * dp];
        float r1 = 1.0f / s[n * DD + 2 * dp + 1];
        pp[i] = make_float4(c[n * DD + 2 * dp] * r0,
                            c[n * DD + 2 * dp + 1] * r1, r0, r1);
    }
}

__global__ __launch_bounds__(256, 2)
void wavelet_kernel(const float* __restrict__ x,
                    const float4* __restrict__ pp,
                    float* __restrict__ out, int B, int N) {
    __shared__ float xls[32][DD];   // block's x strip, 8 KB

    int t = threadIdx.x;
    int lane = t & 63;
    int wv = __builtin_amdgcn_readfirstlane(t >> 6);   // wave-uniform
    int n0 = blockIdx.y * 64;
    int n = n0 + lane;                                 // lane-private column
    int bblk = blockIdx.x * 32;                        // block's 32 b rows

    // one-time cooperative stage of x[bblk..bblk+31][0..63]:
    // 512 float4, 2 per thread, consecutive t -> consecutive 16 B (coalesced)
    {
        const float4* xg = (const float4*)(x + (size_t)bblk * DD);
        float4* xl = (float4*)&xls[0][0];
        xl[t] = xg[t];
        xl[t + 256] = xg[t + 256];
    }
    __syncthreads();   // the only barrier

    const float4* pcol = pp + n;   // pp[dp*N + n], lane-coalesced

    float acc[BSTRIP];
#pragma unroll
    for (int bi = 0; bi < BSTRIP; ++bi) acc[bi] = 1.0f;

#pragma unroll
    for (int h = 0; h < 4; ++h) {          // 4 chunks of 16 d (= overflow group)
        // params for this chunk: VGPR-resident, reused by all 8 b rows
        v2f cp[8], rs[8];
#pragma unroll
        for (int i = 0; i < 8; ++i) {
            float4 q = pcol[(size_t)(h * 8 + i) * N];  // coalesced dwordx4
            cp[i] = (v2f){q.x, q.y};
            rs[i] = (v2f){q.z, q.w};
        }

#pragma unroll
        for (int bi = 0; bi < BSTRIP; ++bi) {
            // x slice: wave-uniform LDS address -> broadcast ds_read_b128,
            // conflict-free, no scalar cache, freely hoistable
            const float4* xq = (const float4*)&xls[wv * BSTRIP + bi][h * 16];
            float4 X0 = xq[0];
            float4 X1 = xq[1];
            float4 X2 = xq[2];
            float4 X3 = xq[3];
            float xs[16] = {X0.x, X0.y, X0.z, X0.w,
                            X1.x, X1.y, X1.z, X1.w,
                            X2.x, X2.y, X2.z, X2.w,
                            X3.x, X3.y, X3.z, X3.w};
            v2f p  = {1.0f, 1.0f};
            v2f s2 = {0.0f, 0.0f};
#pragma unroll
            for (int k = 0; k < 8; ++k) {          // 8 d-pairs = 16 d
                v2f xv = {xs[2 * k], xs[2 * k + 1]};
                v2f z = __builtin_elementwise_fma(xv, rs[k], -cp[k]);
                v2f w = z * z;
                p = __builtin_elementwise_fma(-w, p, p);
                s2 += w;
            }
            // exp(-0.5*s) = exp2(-0.72134752*s), one per 16-d group
            acc[bi] *= (p.x * p.y) *
                       __builtin_exp2f(-0.72134752f * (s2.x + s2.y));
        }
    }

    // stores: lanes = consecutive n -> coalesced
#pragma unroll
    for (int bi = 0; bi < BSTRIP; ++bi)
        out[(size_t)(bblk + wv * BSTRIP + bi) * N + n] = acc[bi];
}

extern "C" void kernel_launch(void* const* d_in, const int* in_sizes, int n_in,
                              void* d_out, int out_size, void* d_ws, size_t ws_size,
                              hipStream_t stream) {
    const float* x = (const float*)d_in[0];
    const float* c = (const float*)d_in[1];
    const float* s = (const float*)d_in[2];
    float* out = (float*)d_out;

    int B = in_sizes[0] / DD;    // 8192
    int N = in_sizes[1] / DD;    // 512

    float4* pp = (float4*)d_ws;  // (DD/2)*N*16 B = 256 KB

    int total = (DD / 2) * N;
    prep<<<(total + 255) / 256, 256, 0, stream>>>(c, s, pp, N);

    // grid: x = b strips of 32 rows (4 waves x 8), y = n/64
    dim3 grid(B / 32, N / 64);   // 256 x 8 = 2048 blocks
    wavelet_kernel<<<grid, 256, 0, stream>>>(x, pp, out, B, N);
}